// Round 7
// baseline (398.807 us; speedup 1.0000x reference)
//
#include <hip/hip_runtime.h>

// ---------------------------------------------------------------------------
// BlockCrossAttention on MI355X (gfx950).  Round 7 (= round 6 + compile fix):
//  - flash: ZERO-LDS inner loop. S^T = K·Q^T via 16x16x32 bf16 MFMA (operand
//    swap); S^T's C-layout is exactly the A-layout of 16x16x16 f16 MFMA, so
//    P packs in-register (f32->f16 casts) straight into PV. Mask folded
//    into V (zeroed rows, GEMM epilogue) and into an extra "L = P·m" MFMA.
//    Waves = 4 qh heads sharing identical K/V addresses (L1 dedup, 4x less
//    L2 traffic). Grid (b,g,split4,strip16) = 1024 WGs, no __shared__.
//  - GEMMs/prep unchanged except V epilogue: f16 + mask-zeroing; mask->f16
//    0/1 array for the L MFMA.
// ---------------------------------------------------------------------------

typedef unsigned short u16;
typedef __attribute__((ext_vector_type(8))) __bf16 bf16x8;
typedef __attribute__((ext_vector_type(4))) float f32x4;
typedef __attribute__((ext_vector_type(4))) _Float16 f16x4;

static __device__ __forceinline__ u16 f2bf(float f) {        // RNE
    unsigned int u = __float_as_uint(f);
    u = (u + 0x7fffu + ((u >> 16) & 1u)) >> 16;
    return (u16)u;
}
static __device__ __forceinline__ void gload16(const u16* g, u16* l) {
    __builtin_amdgcn_global_load_lds(
        (const __attribute__((address_space(1))) void*)g,
        (__attribute__((address_space(3))) void*)l, 16, 0, 0);
}

// ---------------- all prep in one launch -----------------------------------
// [0,2560) weight transposes, [2560,10752) enc cast, [10752,11776) pool,
// 11776: mask -> f16 0/1 array.
__global__ __launch_bounds__(256) void prep_all(const float* __restrict__ enc,
                                                const float* __restrict__ hid,
                                                const int* __restrict__ mask,
                                                const float* __restrict__ Wq,
                                                const float* __restrict__ Wk,
                                                const float* __restrict__ Wv,
                                                const float* __restrict__ Wo,
                                                u16* __restrict__ encb,
                                                u16* __restrict__ poolb,
                                                u16* __restrict__ mh,
                                                u16* __restrict__ Wq_t,
                                                u16* __restrict__ Wkv_t,
                                                u16* __restrict__ Wo_t) {
    int bid = blockIdx.x;
    if (bid < 2560) {                                  // weight transpose+cast
        const float* in; u16* out; int N, nbx, rowoff;
        if (bid < 1024)      { in = Wq; out = Wq_t;  N = 1024; nbx = 32; rowoff = 0; }
        else if (bid < 2048) { in = Wo; out = Wo_t;  N = 1024; nbx = 32; rowoff = 0; bid -= 1024; }
        else if (bid < 2304) { in = Wk; out = Wkv_t; N = 256;  nbx = 8;  rowoff = 0; bid -= 2048; }
        else                 { in = Wv; out = Wkv_t; N = 256;  nbx = 8;  rowoff = 256; bid -= 2304; }
        const int n0 = (bid % nbx) * 32, k0 = (bid / nbx) * 32;
        __shared__ float t[32][33];
        const int tx = threadIdx.x & 31, ty = threadIdx.x >> 5;
#pragma unroll
        for (int i = 0; i < 4; ++i)
            t[ty + 8 * i][tx] = in[(size_t)(k0 + ty + 8 * i) * N + n0 + tx];
        __syncthreads();
#pragma unroll
        for (int i = 0; i < 4; ++i)
            out[(size_t)(rowoff + n0 + ty + 8 * i) * 1024 + k0 + tx] = f2bf(t[tx][ty + 8 * i]);
    } else if (bid < 10752) {                          // enc fp32->bf16 x4
        const int tid = (bid - 2560) * 256 + threadIdx.x;
        float4 v = ((const float4*)enc)[tid];
        ushort4 o;
        o.x = f2bf(v.x); o.y = f2bf(v.y); o.z = f2bf(v.z); o.w = f2bf(v.w);
        ((ushort4*)encb)[tid] = o;
    } else if (bid < 11776) {                          // mean-pool 16 tokens
        const int tid = (bid - 10752) * 256 + threadIdx.x;
        const int c4 = tid & 255;
        const int row = tid >> 8;                      // b*512 + n
        const float4* src = (const float4*)(hid + (size_t)row * 16 * 1024) + c4;
        float4 a = src[0];
#pragma unroll
        for (int t = 1; t < 16; ++t) {
            float4 b = src[(size_t)t * 256];
            a.x += b.x; a.y += b.y; a.z += b.z; a.w += b.w;
        }
        ushort4 o;
        o.x = f2bf(a.x * 0.0625f); o.y = f2bf(a.y * 0.0625f);
        o.z = f2bf(a.z * 0.0625f); o.w = f2bf(a.w * 0.0625f);
        *(ushort4*)(poolb + (size_t)row * 1024 + c4 * 4) = o;
    } else {                                           // mask -> f16 0/1
#pragma unroll
        for (int k = 0; k < 32; ++k) {
            const int i = threadIdx.x + 256 * k;
            mh[i] = mask[i] ? (u16)0x3C00 : (u16)0;    // f16 1.0 / 0.0
        }
    }
}

// ---------------- 64x64 GEMM core, K=1024, global_load_lds staging ---------
// MODE 0: Q -> Qa scatter * 0.125*log2e.  MODE 3: fp32 out[m*1024+c].
// MODE 4: K -> Ka[l][d] bf16; V -> Va^T[d][l] f16 * mask[l] (zeroed rows).
template <int MODE>
static __device__ __forceinline__ void gemm_core(const u16* __restrict__ A,
                                                 const u16* __restrict__ Bt,
                                                 const int* __restrict__ maskp,
                                                 u16* __restrict__ outK,
                                                 u16* __restrict__ outV,
                                                 float* __restrict__ out_f,
                                                 int m0, int n0) {
    __shared__ __align__(16) u16 sAB[2 * 64 * 72];   // staging uses stride 64
    u16* sA = sAB;
    u16* sB = sAB + 64 * 64;
    const int t = threadIdx.x;
    const int w = t >> 6, lane = t & 63, quad = lane >> 4, r16 = lane & 15;
    const int row8 = lane >> 3, seg = lane & 7;

    f32x4 acc[4];
#pragma unroll
    for (int i = 0; i < 4; ++i) acc[i] = (f32x4){0.f, 0.f, 0.f, 0.f};

    for (int kt = 0; kt < 16; ++kt) {
        const int k0 = kt * 64;
        __syncthreads();
#pragma unroll
        for (int j = 0; j < 2; ++j) {
            const int ra = w * 16 + j * 8;
            gload16(A + (size_t)(m0 + ra + row8) * 1024 + k0 + seg * 8, sA + ra * 64);
            gload16(Bt + (size_t)(n0 + ra + row8) * 1024 + k0 + seg * 8, sB + ra * 64);
        }
        __syncthreads();
#pragma unroll
        for (int kk = 0; kk < 2; ++kk) {
            const bf16x8 af = *(const bf16x8*)(sA + (16 * w + r16) * 64 + kk * 32 + quad * 8);
#pragma unroll
            for (int nt = 0; nt < 4; ++nt) {
                const bf16x8 bfv = *(const bf16x8*)(sB + (nt * 16 + r16) * 64 + kk * 32 + quad * 8);
                acc[nt] = __builtin_amdgcn_mfma_f32_16x16x32_bf16(af, bfv, acc[nt], 0, 0, 0);
            }
        }
    }

    if (MODE == 0) {
#pragma unroll
        for (int nt = 0; nt < 4; ++nt)
#pragma unroll
            for (int r = 0; r < 4; ++r) {
                const int m = m0 + 16 * w + quad * 4 + r;
                const int c = n0 + nt * 16 + r16;
                const int b = m >> 9, nq = m & 511, g = c >> 8, qh = (c >> 6) & 3, d = c & 63;
                outK[((((size_t)(b * 4 + g) * 4 + qh) * 512 + nq) << 6) + d] =
                    f2bf(acc[nt][r] * 0.180336880f);   // 0.125*log2(e), exp2 domain
            }
    } else if (MODE == 4) {
        const bool isV = (n0 >= 256);
        const int g = (isV ? (n0 - 256) : n0) >> 6;
        const int b = m0 >> 12, l0 = m0 & 4095;
        u16* sT = sAB;
        __syncthreads();
        if (isV) {
            float mfl[4];
#pragma unroll
            for (int r = 0; r < 4; ++r)
                mfl[r] = maskp[b * 4096 + l0 + 16 * w + quad * 4 + r] ? 1.f : 0.f;
#pragma unroll
            for (int nt = 0; nt < 4; ++nt)
#pragma unroll
                for (int r = 0; r < 4; ++r) {
                    const int ml = 16 * w + quad * 4 + r, cl = nt * 16 + r16;
                    union { _Float16 h; u16 u; } cv;
                    cv.h = (_Float16)(acc[nt][r] * mfl[r]);
                    sT[cl * 72 + ml] = cv.u;           // V^T tile: row=d, col=l
                }
        } else {
#pragma unroll
            for (int nt = 0; nt < 4; ++nt)
#pragma unroll
                for (int r = 0; r < 4; ++r) {
                    const int ml = 16 * w + quad * 4 + r, cl = nt * 16 + r16;
                    sT[ml * 72 + cl] = f2bf(acc[nt][r]);   // K tile: row=l, col=d
                }
        }
        __syncthreads();
#pragma unroll
        for (int p = 0; p < 2; ++p) {
            const int idx = t + 256 * p, rr = idx >> 3, ch = idx & 7;
            const int4 v = *(const int4*)(sT + rr * 72 + ch * 8);
            if (isV)
                *(int4*)(outV + ((size_t)(b * 4 + g) * 64 + rr) * 4096 + l0 + ch * 8) = v;
            else
                *(int4*)(outK + (((size_t)(b * 4 + g) * 4096 + l0 + rr) << 6) + ch * 8) = v;
        }
    } else {                                           // MODE 3: plain fp32
#pragma unroll
        for (int nt = 0; nt < 4; ++nt)
#pragma unroll
            for (int r = 0; r < 4; ++r) {
                const int m = m0 + 16 * w + quad * 4 + r;
                const int c = n0 + nt * 16 + r16;
                out_f[(size_t)m * 1024 + c] = acc[nt][r];
            }
    }
}

__global__ __launch_bounds__(256) void gemm_qkv(const u16* __restrict__ poolb,
                                                const u16* __restrict__ encb,
                                                const u16* __restrict__ Wq_t,
                                                const u16* __restrict__ Wkv_t,
                                                const int* __restrict__ maskp,
                                                u16* __restrict__ Qa,
                                                u16* __restrict__ Ka,
                                                u16* __restrict__ Va) {
    const int bx = blockIdx.x;
    if (bx < 1024) {
        gemm_core<4>(encb, Wkv_t, maskp, Ka, Va, nullptr, (bx & 127) * 64, (bx >> 7) * 64);
    } else {
        const int b = bx - 1024;
        gemm_core<0>(poolb, Wq_t, nullptr, Qa, nullptr, nullptr, (b & 15) * 64, (b >> 4) * 64);
    }
}

__global__ __launch_bounds__(256) void gemm_o(const u16* __restrict__ attn,
                                              const u16* __restrict__ Wo_t,
                                              float* __restrict__ blk) {
    gemm_core<3>(attn, Wo_t, nullptr, nullptr, nullptr, blk, (blockIdx.x & 15) * 64,
                 (blockIdx.x >> 4) * 64);
}

// ---------------- flash attention: zero-LDS, transposed-S ------------------
// grid 1024: bx = ((b*4+g)*4+split)*32 + s16. Waves = 4 qh (identical K/V
// addresses -> L1 dedup). Per 32-token chunk:
//   S^T = K·Q^T  (mfma 16x16x32 bf16, operand swap; D: row=l, col=q)
//   p = exp2(S^T) cast to f16 in-register (A-layout of 16x16x16 MFMA)
//   O += P·V     (mfma 16x16x16 f16, V pre-masked)
//   L += P·m     (mfma 16x16x16 f16 vs f16 0/1 mask fragment)
__global__ __launch_bounds__(256, 4) void flash_attn(const u16* __restrict__ Qa,
                                                     const u16* __restrict__ Ka,
                                                     const u16* __restrict__ Vt,
                                                     const u16* __restrict__ mh,
                                                     float* __restrict__ Opart,
                                                     float* __restrict__ mlpart) {
    const int bx = blockIdx.x;
    const int s16 = bx & 31, rr = bx >> 5;
    const int split = rr & 3, gb = rr >> 2;
    const int g = gb & 3, b = gb >> 2;
    const int t = threadIdx.x;
    const int qh = t >> 6, lane = t & 63, quad = lane >> 4, r16 = lane & 15;

    bf16x8 aq[2];
    {
        const size_t qbase = ((((size_t)(b * 4 + g) * 4 + qh) * 512) + s16 * 16 + r16) * 64;
#pragma unroll
        for (int kk = 0; kk < 2; ++kk)
            aq[kk] = *(const bf16x8*)(Qa + qbase + kk * 32 + quad * 8);
    }
    // lane-fixed base pointers
    const u16* kb = Ka + (size_t)(b * 4 + g) * 4096 * 64 + (size_t)split * 1024 * 64
                       + (size_t)r16 * 64 + quad * 8;                 // + (l0+nt*16)*64 + kk*32
    const u16* vb = Vt + (size_t)(b * 4 + g) * 64 * 4096 + split * 1024
                       + (size_t)r16 * 4096 + quad * 4;               // + dt*16*4096 + l0 + nt*16
    const u16* mb = mh + b * 4096 + split * 1024 + quad * 4;          // + l0 + nt*16

    f32x4 o[4], lacc;
#pragma unroll
    for (int i = 0; i < 4; ++i) o[i] = (f32x4){0.f, 0.f, 0.f, 0.f};
    lacc = (f32x4){0.f, 0.f, 0.f, 0.f};

    bf16x8 bk[2][2];
#pragma unroll
    for (int nt = 0; nt < 2; ++nt)
#pragma unroll
        for (int kk = 0; kk < 2; ++kk)
            bk[nt][kk] = *(const bf16x8*)(kb + (size_t)(nt * 16) * 64 + kk * 32);

    for (int c = 0; c < 32; ++c) {
        const int l0 = c * 32;
        // current chunk V + mask fragments (needed after QK, ~100cyc slack)
        f16x4 bv[2][4], bvm[2];
#pragma unroll
        for (int nt = 0; nt < 2; ++nt) {
            bvm[nt] = *(const f16x4*)(mb + l0 + nt * 16);
#pragma unroll
            for (int dt = 0; dt < 4; ++dt)
                bv[nt][dt] = *(const f16x4*)(vb + (size_t)(dt * 16) * 4096 + l0 + nt * 16);
        }
        // QK: S^T
        f32x4 st[2];
#pragma unroll
        for (int nt = 0; nt < 2; ++nt) st[nt] = (f32x4){0.f, 0.f, 0.f, 0.f};
#pragma unroll
        for (int kk = 0; kk < 2; ++kk)
#pragma unroll
            for (int nt = 0; nt < 2; ++nt)
                st[nt] = __builtin_amdgcn_mfma_f32_16x16x32_bf16(bk[nt][kk], aq[kk], st[nt], 0, 0, 0);
        // prefetch next chunk's K
        if (c < 31) {
#pragma unroll
            for (int nt = 0; nt < 2; ++nt)
#pragma unroll
                for (int kk = 0; kk < 2; ++kk)
                    bk[nt][kk] = *(const bf16x8*)(kb + (size_t)(l0 + 32 + nt * 16) * 64 + kk * 32);
        }
        // softmax numerators, cast to f16 A-fragments in-register (RNE)
        f16x4 pa[2];
#pragma unroll
        for (int nt = 0; nt < 2; ++nt)
#pragma unroll
            for (int j = 0; j < 4; ++j)
                pa[nt][j] = (_Float16)__builtin_amdgcn_exp2f(st[nt][j]);
        // L += P·m ; O += P·V
#pragma unroll
        for (int nt = 0; nt < 2; ++nt) {
            lacc = __builtin_amdgcn_mfma_f32_16x16x16f16(pa[nt], bvm[nt], lacc, 0, 0, 0);
#pragma unroll
            for (int dt = 0; dt < 4; ++dt)
                o[dt] = __builtin_amdgcn_mfma_f32_16x16x16f16(pa[nt], bv[nt][dt], o[dt], 0, 0, 0);
        }
    }

    // D layout: row(quad*4+r) = query q, col(r16) = d (for o) / replicated (lacc)
    const size_t pbase = ((size_t)bx * 4 + qh) * 1024;
#pragma unroll
    for (int dt = 0; dt < 4; ++dt)
#pragma unroll
        for (int r = 0; r < 4; ++r)
            Opart[pbase + (size_t)(quad * 4 + r) * 64 + dt * 16 + r16] = o[dt][r];
    if (r16 == 0) {
#pragma unroll
        for (int r = 0; r < 4; ++r)
            mlpart[((size_t)bx * 4 + qh) * 16 + quad * 4 + r] = lacc[r];
    }
}

// ---------------- combine 4 split partials -> normalized attn (bf16) -------
__global__ __launch_bounds__(256) void flash_combine(const float* __restrict__ Opart,
                                                     const float* __restrict__ mlpart,
                                                     u16* __restrict__ attnout) {
    const int bx = blockIdx.x;                  // tile (b,g,qh,s16)
    const int s16 = bx & 31, h = bx >> 5;
    const int qh = h & 3, g = (h >> 2) & 3, b = h >> 4;
    const int t = threadIdx.x;
    const int q = t >> 4, dg = t & 15;
    float4 a = make_float4(0.f, 0.f, 0.f, 0.f);
    float L = 0.f;
#pragma unroll
    for (int s = 0; s < 4; ++s) {
        const size_t part = (((size_t)((b * 4 + g) * 4 + s) * 32 + s16) * 4 + qh);
        const float4 v = *(const float4*)(Opart + part * 1024 + q * 64 + dg * 4);
        a.x += v.x; a.y += v.y; a.z += v.z; a.w += v.w;
        L += mlpart[part * 16 + q];
    }
    const float invL = 1.f / L;
    ushort4 ov;
    ov.x = f2bf(a.x * invL); ov.y = f2bf(a.y * invL);
    ov.z = f2bf(a.z * invL); ov.w = f2bf(a.w * invL);
    *(ushort4*)(attnout + ((size_t)b * 512 + s16 * 16 + q) * 1024 +
                (g * 4 + qh) * 64 + dg * 4) = ov;
}

// ---------------- broadcast block output x16 to token level ----------------
__global__ __launch_bounds__(256) void bcast_out(const float* __restrict__ blockout,
                                                 float* __restrict__ out) {
    const int tid = blockIdx.x * 256 + threadIdx.x;   // 4,194,304 float4s
    const int c4 = tid & 255;
    const int row = tid >> 8;                          // b*8192 + l
    const int b = row >> 13, l = row & 8191;
    ((float4*)out)[tid] = ((const float4*)blockout)[((size_t)(b * 512 + (l >> 4)) << 8) + c4];
}

// ---------------------------------------------------------------------------
extern "C" void kernel_launch(void* const* d_in, const int* in_sizes, int n_in,
                              void* d_out, int out_size, void* d_ws, size_t ws_size,
                              hipStream_t stream) {
    const float* hid  = (const float*)d_in[0];
    const float* enc  = (const float*)d_in[1];
    const int*   mask = (const int*)d_in[2];
    const float* Wq   = (const float*)d_in[3];
    const float* Wk   = (const float*)d_in[4];
    const float* Wv   = (const float*)d_in[5];
    const float* Wo   = (const float*)d_in[6];
    float* out = (float*)d_out;

    char* ws = (char*)d_ws;
    size_t off = 0;
    auto alloc = [&](size_t bytes) -> char* {
        char* p = ws + off;
        off += (bytes + 255) & ~(size_t)255;
        return p;
    };
    u16* Wq_t  = (u16*)alloc((size_t)1024 * 1024 * 2);
    u16* Wkv_t = (u16*)alloc((size_t)512 * 1024 * 2);
    u16* Wo_t  = (u16*)alloc((size_t)1024 * 1024 * 2);
    u16* encb  = (u16*)alloc((size_t)8192 * 1024 * 2);     // 16 MB
    u16* poolb = (u16*)alloc((size_t)1024 * 1024 * 2);     // 2 MB
    u16* Qa    = (u16*)alloc((size_t)1024 * 1024 * 2);
    u16* Ka    = (u16*)alloc((size_t)8 * 4096 * 64 * 2);   // bf16 [l][d]
    u16* Va    = (u16*)alloc((size_t)8 * 4096 * 64 * 2);   // f16  [d][l], masked
    u16* attn  = (u16*)alloc((size_t)1024 * 1024 * 2);
    float* blk = (float*)alloc((size_t)1024 * 1024 * 4);
    u16* mh    = (u16*)alloc((size_t)8192 * 2);            // f16 0/1 mask
    // aliases: dead after their GEMM consumers, reused by flash partials
    float* Opart  = (float*)encb;    // 4096 tiles x 16x64 fp32 = 16 MB
    float* mlpart = (float*)poolb;   // 4096 x 16 fp32 = 256 KB

    prep_all<<<11777, 256, 0, stream>>>(enc, hid, mask, Wq, Wk, Wv, Wo,
                                        encb, poolb, mh, Wq_t, Wkv_t, Wo_t);
    gemm_qkv<<<1280, 256, 0, stream>>>(poolb, encb, Wq_t, Wkv_t, mask, Qa, Ka, Va);
    flash_attn<<<1024, 256, 0, stream>>>(Qa, Ka, Va, mh, Opart, mlpart);
    flash_combine<<<1024, 256, 0, stream>>>(Opart, mlpart, attn);
    gemm_o<<<256, 256, 0, stream>>>(attn, Wo_t, blk);
    bcast_out<<<16384, 256, 0, stream>>>(blk, out);
}

// Round 8
// 253.235 us; speedup vs baseline: 1.5748x; 1.5748x over previous
//
#include <hip/hip_runtime.h>

// ---------------------------------------------------------------------------
// BlockCrossAttention on MI355X (gfx950).  Round 8:
//  - flash hybrid: r2's dense WG-shared K/V LDS staging + r3's fixed-base
//    exp2 softmax + r7's verified in-register P (S^T = K·Q^T, f16 A-frags,
//    PV + L-via-mask MFMA). No P LDS roundtrip, no shuffles in loop, no
//    scattered global fragment reads. Waves = 4 qh heads sharing K/V tile.
//    V staged transposed ([d][l], stride 68 -> contiguous 8B PV ds_reads).
//  - gemm_qkv: n-inner block swizzle (consecutive WGs share A-tile in L2).
// ---------------------------------------------------------------------------

typedef unsigned short u16;
typedef __attribute__((ext_vector_type(8))) __bf16 bf16x8;
typedef __attribute__((ext_vector_type(4))) float f32x4;
typedef __attribute__((ext_vector_type(4))) _Float16 f16x4;

static __device__ __forceinline__ u16 f2bf(float f) {        // RNE
    unsigned int u = __float_as_uint(f);
    u = (u + 0x7fffu + ((u >> 16) & 1u)) >> 16;
    return (u16)u;
}
static __device__ __forceinline__ void gload16(const u16* g, u16* l) {
    __builtin_amdgcn_global_load_lds(
        (const __attribute__((address_space(1))) void*)g,
        (__attribute__((address_space(3))) void*)l, 16, 0, 0);
}

// ---------------- all prep in one launch -----------------------------------
// [0,2560) weight transposes, [2560,10752) enc cast, [10752,11776) pool,
// 11776: mask -> f16 0/1 array.
__global__ __launch_bounds__(256) void prep_all(const float* __restrict__ enc,
                                                const float* __restrict__ hid,
                                                const int* __restrict__ mask,
                                                const float* __restrict__ Wq,
                                                const float* __restrict__ Wk,
                                                const float* __restrict__ Wv,
                                                const float* __restrict__ Wo,
                                                u16* __restrict__ encb,
                                                u16* __restrict__ poolb,
                                                u16* __restrict__ mh,
                                                u16* __restrict__ Wq_t,
                                                u16* __restrict__ Wkv_t,
                                                u16* __restrict__ Wo_t) {
    int bid = blockIdx.x;
    if (bid < 2560) {                                  // weight transpose+cast
        const float* in; u16* out; int N, nbx, rowoff;
        if (bid < 1024)      { in = Wq; out = Wq_t;  N = 1024; nbx = 32; rowoff = 0; }
        else if (bid < 2048) { in = Wo; out = Wo_t;  N = 1024; nbx = 32; rowoff = 0; bid -= 1024; }
        else if (bid < 2304) { in = Wk; out = Wkv_t; N = 256;  nbx = 8;  rowoff = 0; bid -= 2048; }
        else                 { in = Wv; out = Wkv_t; N = 256;  nbx = 8;  rowoff = 256; bid -= 2304; }
        const int n0 = (bid % nbx) * 32, k0 = (bid / nbx) * 32;
        __shared__ float t[32][33];
        const int tx = threadIdx.x & 31, ty = threadIdx.x >> 5;
#pragma unroll
        for (int i = 0; i < 4; ++i)
            t[ty + 8 * i][tx] = in[(size_t)(k0 + ty + 8 * i) * N + n0 + tx];
        __syncthreads();
#pragma unroll
        for (int i = 0; i < 4; ++i)
            out[(size_t)(rowoff + n0 + ty + 8 * i) * 1024 + k0 + tx] = f2bf(t[tx][ty + 8 * i]);
    } else if (bid < 10752) {                          // enc fp32->bf16 x4
        const int tid = (bid - 2560) * 256 + threadIdx.x;
        float4 v = ((const float4*)enc)[tid];
        ushort4 o;
        o.x = f2bf(v.x); o.y = f2bf(v.y); o.z = f2bf(v.z); o.w = f2bf(v.w);
        ((ushort4*)encb)[tid] = o;
    } else if (bid < 11776) {                          // mean-pool 16 tokens
        const int tid = (bid - 10752) * 256 + threadIdx.x;
        const int c4 = tid & 255;
        const int row = tid >> 8;                      // b*512 + n
        const float4* src = (const float4*)(hid + (size_t)row * 16 * 1024) + c4;
        float4 a = src[0];
#pragma unroll
        for (int t = 1; t < 16; ++t) {
            float4 b = src[(size_t)t * 256];
            a.x += b.x; a.y += b.y; a.z += b.z; a.w += b.w;
        }
        ushort4 o;
        o.x = f2bf(a.x * 0.0625f); o.y = f2bf(a.y * 0.0625f);
        o.z = f2bf(a.z * 0.0625f); o.w = f2bf(a.w * 0.0625f);
        *(ushort4*)(poolb + (size_t)row * 1024 + c4 * 4) = o;
    } else {                                           // mask -> f16 0/1
#pragma unroll
        for (int k = 0; k < 32; ++k) {
            const int i = threadIdx.x + 256 * k;
            mh[i] = mask[i] ? (u16)0x3C00 : (u16)0;    // f16 1.0 / 0.0
        }
    }
}

// ---------------- 64x64 GEMM core, K=1024, global_load_lds staging ---------
// MODE 0: Q -> Qa scatter * 0.125*log2e.  MODE 3: fp32 out[m*1024+c].
// MODE 4: K -> Ka[l][d] bf16; V -> Va^T[d][l] f16 * mask[l] (zeroed rows).
template <int MODE>
static __device__ __forceinline__ void gemm_core(const u16* __restrict__ A,
                                                 const u16* __restrict__ Bt,
                                                 const int* __restrict__ maskp,
                                                 u16* __restrict__ outK,
                                                 u16* __restrict__ outV,
                                                 float* __restrict__ out_f,
                                                 int m0, int n0) {
    __shared__ __align__(16) u16 sAB[2 * 64 * 72];   // staging uses stride 64
    u16* sA = sAB;
    u16* sB = sAB + 64 * 64;
    const int t = threadIdx.x;
    const int w = t >> 6, lane = t & 63, quad = lane >> 4, r16 = lane & 15;
    const int row8 = lane >> 3, seg = lane & 7;

    f32x4 acc[4];
#pragma unroll
    for (int i = 0; i < 4; ++i) acc[i] = (f32x4){0.f, 0.f, 0.f, 0.f};

    for (int kt = 0; kt < 16; ++kt) {
        const int k0 = kt * 64;
        __syncthreads();
#pragma unroll
        for (int j = 0; j < 2; ++j) {
            const int ra = w * 16 + j * 8;
            gload16(A + (size_t)(m0 + ra + row8) * 1024 + k0 + seg * 8, sA + ra * 64);
            gload16(Bt + (size_t)(n0 + ra + row8) * 1024 + k0 + seg * 8, sB + ra * 64);
        }
        __syncthreads();
#pragma unroll
        for (int kk = 0; kk < 2; ++kk) {
            const bf16x8 af = *(const bf16x8*)(sA + (16 * w + r16) * 64 + kk * 32 + quad * 8);
#pragma unroll
            for (int nt = 0; nt < 4; ++nt) {
                const bf16x8 bfv = *(const bf16x8*)(sB + (nt * 16 + r16) * 64 + kk * 32 + quad * 8);
                acc[nt] = __builtin_amdgcn_mfma_f32_16x16x32_bf16(af, bfv, acc[nt], 0, 0, 0);
            }
        }
    }

    if (MODE == 0) {
#pragma unroll
        for (int nt = 0; nt < 4; ++nt)
#pragma unroll
            for (int r = 0; r < 4; ++r) {
                const int m = m0 + 16 * w + quad * 4 + r;
                const int c = n0 + nt * 16 + r16;
                const int b = m >> 9, nq = m & 511, g = c >> 8, qh = (c >> 6) & 3, d = c & 63;
                outK[((((size_t)(b * 4 + g) * 4 + qh) * 512 + nq) << 6) + d] =
                    f2bf(acc[nt][r] * 0.180336880f);   // 0.125*log2(e), exp2 domain
            }
    } else if (MODE == 4) {
        const bool isV = (n0 >= 256);
        const int g = (isV ? (n0 - 256) : n0) >> 6;
        const int b = m0 >> 12, l0 = m0 & 4095;
        u16* sT = sAB;
        __syncthreads();
        if (isV) {
            float mfl[4];
#pragma unroll
            for (int r = 0; r < 4; ++r)
                mfl[r] = maskp[b * 4096 + l0 + 16 * w + quad * 4 + r] ? 1.f : 0.f;
#pragma unroll
            for (int nt = 0; nt < 4; ++nt)
#pragma unroll
                for (int r = 0; r < 4; ++r) {
                    const int ml = 16 * w + quad * 4 + r, cl = nt * 16 + r16;
                    union { _Float16 h; u16 u; } cv;
                    cv.h = (_Float16)(acc[nt][r] * mfl[r]);
                    sT[cl * 72 + ml] = cv.u;           // V^T tile: row=d, col=l
                }
        } else {
#pragma unroll
            for (int nt = 0; nt < 4; ++nt)
#pragma unroll
                for (int r = 0; r < 4; ++r) {
                    const int ml = 16 * w + quad * 4 + r, cl = nt * 16 + r16;
                    sT[ml * 72 + cl] = f2bf(acc[nt][r]);   // K tile: row=l, col=d
                }
        }
        __syncthreads();
#pragma unroll
        for (int p = 0; p < 2; ++p) {
            const int idx = t + 256 * p, rr = idx >> 3, ch = idx & 7;
            const int4 v = *(const int4*)(sT + rr * 72 + ch * 8);
            if (isV)
                *(int4*)(outV + ((size_t)(b * 4 + g) * 64 + rr) * 4096 + l0 + ch * 8) = v;
            else
                *(int4*)(outK + (((size_t)(b * 4 + g) * 4096 + l0 + rr) << 6) + ch * 8) = v;
        }
    } else {                                           // MODE 3: plain fp32
#pragma unroll
        for (int nt = 0; nt < 4; ++nt)
#pragma unroll
            for (int r = 0; r < 4; ++r) {
                const int m = m0 + 16 * w + quad * 4 + r;
                const int c = n0 + nt * 16 + r16;
                out_f[(size_t)m * 1024 + c] = acc[nt][r];
            }
    }
}

// n-inner swizzle: consecutive WGs share the same A-tile (L2 reuse)
__global__ __launch_bounds__(256) void gemm_qkv(const u16* __restrict__ poolb,
                                                const u16* __restrict__ encb,
                                                const u16* __restrict__ Wq_t,
                                                const u16* __restrict__ Wkv_t,
                                                const int* __restrict__ maskp,
                                                u16* __restrict__ Qa,
                                                u16* __restrict__ Ka,
                                                u16* __restrict__ Va) {
    const int bx = blockIdx.x;
    if (bx < 1024) {
        gemm_core<4>(encb, Wkv_t, maskp, Ka, Va, nullptr, (bx >> 3) * 64, (bx & 7) * 64);
    } else {
        const int b = bx - 1024;
        gemm_core<0>(poolb, Wq_t, nullptr, Qa, nullptr, nullptr, (b >> 4) * 64, (b & 15) * 64);
    }
}

__global__ __launch_bounds__(256) void gemm_o(const u16* __restrict__ attn,
                                              const u16* __restrict__ Wo_t,
                                              float* __restrict__ blk) {
    gemm_core<3>(attn, Wo_t, nullptr, nullptr, nullptr, blk, (blockIdx.x >> 4) * 64,
                 (blockIdx.x & 15) * 64);
}

// ---------------- flash attention: LDS-staged, in-register P ---------------
// grid 1024: bx = ((b*4+g)*4+split)*32 + s16. Waves = 4 qh sharing the staged
// K/V tile. Per 64-token tile:
//   stage K[l][d] (stride 72) + V^T[d][l] (stride 68) cooperatively
//   S^T = K·Q^T   (mfma 16x16x32 bf16; K LDS-frags as A, Q regs as B)
//   p = exp2(S^T) cast f16 in-register -> A-frags of 16x16x16 f16
//   O += P·V      (V^T LDS-frags: contiguous 8B ds_reads)
//   L += P·m      (f16 0/1 mask frags from global, L1-hot)
__global__ __launch_bounds__(256, 4) void flash_attn(const u16* __restrict__ Qa,
                                                     const u16* __restrict__ Ka,
                                                     const u16* __restrict__ Vt,
                                                     const u16* __restrict__ mh,
                                                     float* __restrict__ Opart,
                                                     float* __restrict__ mlpart) {
    const int bx = blockIdx.x;
    const int s16 = bx & 31, rr = bx >> 5;
    const int split = rr & 3, gb = rr >> 2;
    const int g = gb & 3, b = gb >> 2;
    __shared__ __align__(16) u16 sK[64 * 72];        // [l][d] bf16
    __shared__ __align__(16) u16 sV[64 * 68];        // [d][l] f16 (V^T)
    const int t = threadIdx.x;
    const int qh = t >> 6, lane = t & 63, quad = lane >> 4, r16 = lane & 15;

    bf16x8 aq[2];
    {
        const size_t qbase = ((((size_t)(b * 4 + g) * 4 + qh) * 512) + s16 * 16 + r16) * 64;
#pragma unroll
        for (int kk = 0; kk < 2; ++kk)
            aq[kk] = *(const bf16x8*)(Qa + qbase + kk * 32 + quad * 8);
    }
    const u16* Kg = Ka + (size_t)(b * 4 + g) * 4096 * 64 + (size_t)split * 1024 * 64; // [l][d]
    const u16* Vg = Vt + (size_t)(b * 4 + g) * 64 * 4096 + split * 1024;              // [d][l]
    const u16* mb = mh + b * 4096 + split * 1024 + quad * 4;

    f32x4 o[4], lacc;
#pragma unroll
    for (int i = 0; i < 4; ++i) o[i] = (f32x4){0.f, 0.f, 0.f, 0.f};
    lacc = (f32x4){0.f, 0.f, 0.f, 0.f};

    for (int tile = 0; tile < 16; ++tile) {
        const int l0 = tile * 64;
        __syncthreads();
#pragma unroll
        for (int p = 0; p < 2; ++p) {
            const int idx = t + 256 * p, row = idx >> 3, seg = idx & 7;
            *(int4*)(sK + row * 72 + seg * 8) =
                *(const int4*)(Kg + (size_t)(l0 + row) * 64 + seg * 8);
            *(int4*)(sV + row * 68 + seg * 8) =
                *(const int4*)(Vg + (size_t)row * 4096 + l0 + seg * 8);
        }
        __syncthreads();

        // S^T[l][q]: K frags from LDS as A-operand, Q regs as B
        f32x4 st[4];
#pragma unroll
        for (int nt = 0; nt < 4; ++nt) st[nt] = (f32x4){0.f, 0.f, 0.f, 0.f};
#pragma unroll
        for (int kk = 0; kk < 2; ++kk)
#pragma unroll
            for (int nt = 0; nt < 4; ++nt) {
                const bf16x8 ka = *(const bf16x8*)(sK + (nt * 16 + r16) * 72 + kk * 32 + quad * 8);
                st[nt] = __builtin_amdgcn_mfma_f32_16x16x32_bf16(ka, aq[kk], st[nt], 0, 0, 0);
            }

        // p = exp2(s) -> f16 A-frags (P[q][l-chunk]); L and O via MFMA
#pragma unroll
        for (int nt = 0; nt < 4; ++nt) {
            f16x4 pa;
#pragma unroll
            for (int j = 0; j < 4; ++j)
                pa[j] = (_Float16)__builtin_amdgcn_exp2f(st[nt][j]);
            const f16x4 bvm = *(const f16x4*)(mb + l0 + nt * 16);
            lacc = __builtin_amdgcn_mfma_f32_16x16x16f16(pa, bvm, lacc, 0, 0, 0);
#pragma unroll
            for (int dt = 0; dt < 4; ++dt) {
                const f16x4 bv = *(const f16x4*)(sV + (dt * 16 + r16) * 68 + nt * 16 + quad * 4);
                o[dt] = __builtin_amdgcn_mfma_f32_16x16x16f16(pa, bv, o[dt], 0, 0, 0);
            }
        }
    }

    // D layout: row(quad*4+r) = query q, col(r16) = d (o) / replicated (lacc)
    const size_t pbase = ((size_t)bx * 4 + qh) * 1024;
#pragma unroll
    for (int dt = 0; dt < 4; ++dt)
#pragma unroll
        for (int r = 0; r < 4; ++r)
            Opart[pbase + (size_t)(quad * 4 + r) * 64 + dt * 16 + r16] = o[dt][r];
    if (r16 == 0) {
#pragma unroll
        for (int r = 0; r < 4; ++r)
            mlpart[((size_t)bx * 4 + qh) * 16 + quad * 4 + r] = lacc[r];
    }
}

// ---------------- combine 4 split partials -> normalized attn (bf16) -------
__global__ __launch_bounds__(256) void flash_combine(const float* __restrict__ Opart,
                                                     const float* __restrict__ mlpart,
                                                     u16* __restrict__ attnout) {
    const int bx = blockIdx.x;                  // tile (b,g,qh,s16)
    const int s16 = bx & 31, h = bx >> 5;
    const int qh = h & 3, g = (h >> 2) & 3, b = h >> 4;
    const int t = threadIdx.x;
    const int q = t >> 4, dg = t & 15;
    float4 a = make_float4(0.f, 0.f, 0.f, 0.f);
    float L = 0.f;
#pragma unroll
    for (int s = 0; s < 4; ++s) {
        const size_t part = (((size_t)((b * 4 + g) * 4 + s) * 32 + s16) * 4 + qh);
        const float4 v = *(const float4*)(Opart + part * 1024 + q * 64 + dg * 4);
        a.x += v.x; a.y += v.y; a.z += v.z; a.w += v.w;
        L += mlpart[part * 16 + q];
    }
    const float invL = 1.f / L;
    ushort4 ov;
    ov.x = f2bf(a.x * invL); ov.y = f2bf(a.y * invL);
    ov.z = f2bf(a.z * invL); ov.w = f2bf(a.w * invL);
    *(ushort4*)(attnout + ((size_t)b * 512 + s16 * 16 + q) * 1024 +
                (g * 4 + qh) * 64 + dg * 4) = ov;
}

// ---------------- broadcast block output x16 to token level ----------------
__global__ __launch_bounds__(256) void bcast_out(const float* __restrict__ blockout,
                                                 float* __restrict__ out) {
    const int tid = blockIdx.x * 256 + threadIdx.x;   // 4,194,304 float4s
    const int c4 = tid & 255;
    const int row = tid >> 8;                          // b*8192 + l
    const int b = row >> 13, l = row & 8191;
    ((float4*)out)[tid] = ((const float4*)blockout)[((size_t)(b * 512 + (l >> 4)) << 8) + c4];
}

// ---------------------------------------------------------------------------
extern "C" void kernel_launch(void* const* d_in, const int* in_sizes, int n_in,
                              void* d_out, int out_size, void* d_ws, size_t ws_size,
                              hipStream_t stream) {
    const float* hid  = (const float*)d_in[0];
    const float* enc  = (const float*)d_in[1];
    const int*   mask = (const int*)d_in[2];
    const float* Wq   = (const float*)d_in[3];
    const float* Wk   = (const float*)d_in[4];
    const float* Wv   = (const float*)d_in[5];
    const float* Wo   = (const float*)d_in[6];
    float* out = (float*)d_out;

    char* ws = (char*)d_ws;
    size_t off = 0;
    auto alloc = [&](size_t bytes) -> char* {
        char* p = ws + off;
        off += (bytes + 255) & ~(size_t)255;
        return p;
    };
    u16* Wq_t  = (u16*)alloc((size_t)1024 * 1024 * 2);
    u16* Wkv_t = (u16*)alloc((size_t)512 * 1024 * 2);
    u16* Wo_t  = (u16*)alloc((size_t)1024 * 1024 * 2);
    u16* encb  = (u16*)alloc((size_t)8192 * 1024 * 2);     // 16 MB
    u16* poolb = (u16*)alloc((size_t)1024 * 1024 * 2);     // 2 MB
    u16* Qa    = (u16*)alloc((size_t)1024 * 1024 * 2);
    u16* Ka    = (u16*)alloc((size_t)8 * 4096 * 64 * 2);   // bf16 [l][d]
    u16* Va    = (u16*)alloc((size_t)8 * 4096 * 64 * 2);   // f16  [d][l], masked
    u16* attn  = (u16*)alloc((size_t)1024 * 1024 * 2);
    float* blk = (float*)alloc((size_t)1024 * 1024 * 4);
    u16* mh    = (u16*)alloc((size_t)8192 * 2);            // f16 0/1 mask
    // aliases: dead after their GEMM consumers, reused by flash partials
    float* Opart  = (float*)encb;    // 4096 tiles x 16x64 fp32 = 16 MB
    float* mlpart = (float*)poolb;   // 4096 x 16 fp32 = 256 KB

    prep_all<<<11777, 256, 0, stream>>>(enc, hid, mask, Wq, Wk, Wv, Wo,
                                        encb, poolb, mh, Wq_t, Wkv_t, Wo_t);
    gemm_qkv<<<1280, 256, 0, stream>>>(poolb, encb, Wq_t, Wkv_t, mask, Qa, Ka, Va);
    flash_attn<<<1024, 256, 0, stream>>>(Qa, Ka, Va, mh, Opart, mlpart);
    flash_combine<<<1024, 256, 0, stream>>>(Opart, mlpart, attn);
    gemm_o<<<256, 256, 0, stream>>>(attn, Wo_t, blk);
    bcast_out<<<16384, 256, 0, stream>>>(blk, out);
}

// Round 9
// 248.504 us; speedup vs baseline: 1.6048x; 1.0190x over previous
//
#include <hip/hip_runtime.h>

// ---------------------------------------------------------------------------
// BlockCrossAttention on MI355X (gfx950).  Round 9 (= r8 + three fixes):
//  - prep_all: enc-cast segment gets 4x ILP (4 independent float4 per thread)
//  - gemm_o: split-K-4 (grid 1024 = 4 WG/CU, 4 K-iters each) -> fp32 partials
//  - bcast_out: sums the 4 partials and broadcasts x16 (no blk roundtrip)
//  - flash (r8 hybrid: LDS-staged K/V, in-register P, mask-MFMA) unchanged
// ---------------------------------------------------------------------------

typedef unsigned short u16;
typedef __attribute__((ext_vector_type(8))) __bf16 bf16x8;
typedef __attribute__((ext_vector_type(4))) float f32x4;
typedef __attribute__((ext_vector_type(4))) _Float16 f16x4;

static __device__ __forceinline__ u16 f2bf(float f) {        // RNE
    unsigned int u = __float_as_uint(f);
    u = (u + 0x7fffu + ((u >> 16) & 1u)) >> 16;
    return (u16)u;
}
static __device__ __forceinline__ void gload16(const u16* g, u16* l) {
    __builtin_amdgcn_global_load_lds(
        (const __attribute__((address_space(1))) void*)g,
        (__attribute__((address_space(3))) void*)l, 16, 0, 0);
}

// ---------------- all prep in one launch -----------------------------------
// [0,2560) weight transposes, [2560,4608) enc cast (x4 ILP),
// [4608,5632) pool, 5632: mask -> f16 0/1 array.
__global__ __launch_bounds__(256) void prep_all(const float* __restrict__ enc,
                                                const float* __restrict__ hid,
                                                const int* __restrict__ mask,
                                                const float* __restrict__ Wq,
                                                const float* __restrict__ Wk,
                                                const float* __restrict__ Wv,
                                                const float* __restrict__ Wo,
                                                u16* __restrict__ encb,
                                                u16* __restrict__ poolb,
                                                u16* __restrict__ mh,
                                                u16* __restrict__ Wq_t,
                                                u16* __restrict__ Wkv_t,
                                                u16* __restrict__ Wo_t) {
    int bid = blockIdx.x;
    if (bid < 2560) {                                  // weight transpose+cast
        const float* in; u16* out; int N, nbx, rowoff;
        if (bid < 1024)      { in = Wq; out = Wq_t;  N = 1024; nbx = 32; rowoff = 0; }
        else if (bid < 2048) { in = Wo; out = Wo_t;  N = 1024; nbx = 32; rowoff = 0; bid -= 1024; }
        else if (bid < 2304) { in = Wk; out = Wkv_t; N = 256;  nbx = 8;  rowoff = 0; bid -= 2048; }
        else                 { in = Wv; out = Wkv_t; N = 256;  nbx = 8;  rowoff = 256; bid -= 2304; }
        const int n0 = (bid % nbx) * 32, k0 = (bid / nbx) * 32;
        __shared__ float t[32][33];
        const int tx = threadIdx.x & 31, ty = threadIdx.x >> 5;
#pragma unroll
        for (int i = 0; i < 4; ++i)
            t[ty + 8 * i][tx] = in[(size_t)(k0 + ty + 8 * i) * N + n0 + tx];
        __syncthreads();
#pragma unroll
        for (int i = 0; i < 4; ++i)
            out[(size_t)(rowoff + n0 + ty + 8 * i) * 1024 + k0 + tx] = f2bf(t[tx][ty + 8 * i]);
    } else if (bid < 4608) {                           // enc fp32->bf16, x4 ILP
        const int base = (bid - 2560) * 1024 + threadIdx.x;
        float4 v[4];
#pragma unroll
        for (int j = 0; j < 4; ++j) v[j] = ((const float4*)enc)[base + j * 256];
#pragma unroll
        for (int j = 0; j < 4; ++j) {
            ushort4 o;
            o.x = f2bf(v[j].x); o.y = f2bf(v[j].y);
            o.z = f2bf(v[j].z); o.w = f2bf(v[j].w);
            ((ushort4*)encb)[base + j * 256] = o;
        }
    } else if (bid < 5632) {                           // mean-pool 16 tokens
        const int tid = (bid - 4608) * 256 + threadIdx.x;
        const int c4 = tid & 255;
        const int row = tid >> 8;                      // b*512 + n
        const float4* src = (const float4*)(hid + (size_t)row * 16 * 1024) + c4;
        float4 a = src[0];
#pragma unroll
        for (int t = 1; t < 16; ++t) {
            float4 b = src[(size_t)t * 256];
            a.x += b.x; a.y += b.y; a.z += b.z; a.w += b.w;
        }
        ushort4 o;
        o.x = f2bf(a.x * 0.0625f); o.y = f2bf(a.y * 0.0625f);
        o.z = f2bf(a.z * 0.0625f); o.w = f2bf(a.w * 0.0625f);
        *(ushort4*)(poolb + (size_t)row * 1024 + c4 * 4) = o;
    } else {                                           // mask -> f16 0/1
#pragma unroll
        for (int k = 0; k < 32; ++k) {
            const int i = threadIdx.x + 256 * k;
            mh[i] = mask[i] ? (u16)0x3C00 : (u16)0;    // f16 1.0 / 0.0
        }
    }
}

// ---------------- 64x64 GEMM core, global_load_lds staging -----------------
// MODE 0: Q -> Qa scatter * 0.125*log2e.  MODE 3: fp32 out[m*1024+c].
// MODE 4: K -> Ka[l][d] bf16; V -> Va^T[d][l] f16 * mask[l] (zeroed rows).
// K-range [kt0, kt0+nkt) of 64-wide slices.
template <int MODE>
static __device__ __forceinline__ void gemm_core(const u16* __restrict__ A,
                                                 const u16* __restrict__ Bt,
                                                 const int* __restrict__ maskp,
                                                 u16* __restrict__ outK,
                                                 u16* __restrict__ outV,
                                                 float* __restrict__ out_f,
                                                 int m0, int n0, int kt0, int nkt) {
    __shared__ __align__(16) u16 sAB[2 * 64 * 72];   // staging uses stride 64
    u16* sA = sAB;
    u16* sB = sAB + 64 * 64;
    const int t = threadIdx.x;
    const int w = t >> 6, lane = t & 63, quad = lane >> 4, r16 = lane & 15;
    const int row8 = lane >> 3, seg = lane & 7;

    f32x4 acc[4];
#pragma unroll
    for (int i = 0; i < 4; ++i) acc[i] = (f32x4){0.f, 0.f, 0.f, 0.f};

    for (int kt = kt0; kt < kt0 + nkt; ++kt) {
        const int k0 = kt * 64;
        __syncthreads();
#pragma unroll
        for (int j = 0; j < 2; ++j) {
            const int ra = w * 16 + j * 8;
            gload16(A + (size_t)(m0 + ra + row8) * 1024 + k0 + seg * 8, sA + ra * 64);
            gload16(Bt + (size_t)(n0 + ra + row8) * 1024 + k0 + seg * 8, sB + ra * 64);
        }
        __syncthreads();
#pragma unroll
        for (int kk = 0; kk < 2; ++kk) {
            const bf16x8 af = *(const bf16x8*)(sA + (16 * w + r16) * 64 + kk * 32 + quad * 8);
#pragma unroll
            for (int nt = 0; nt < 4; ++nt) {
                const bf16x8 bfv = *(const bf16x8*)(sB + (nt * 16 + r16) * 64 + kk * 32 + quad * 8);
                acc[nt] = __builtin_amdgcn_mfma_f32_16x16x32_bf16(af, bfv, acc[nt], 0, 0, 0);
            }
        }
    }

    if (MODE == 0) {
#pragma unroll
        for (int nt = 0; nt < 4; ++nt)
#pragma unroll
            for (int r = 0; r < 4; ++r) {
                const int m = m0 + 16 * w + quad * 4 + r;
                const int c = n0 + nt * 16 + r16;
                const int b = m >> 9, nq = m & 511, g = c >> 8, qh = (c >> 6) & 3, d = c & 63;
                outK[((((size_t)(b * 4 + g) * 4 + qh) * 512 + nq) << 6) + d] =
                    f2bf(acc[nt][r] * 0.180336880f);   // 0.125*log2(e), exp2 domain
            }
    } else if (MODE == 4) {
        const bool isV = (n0 >= 256);
        const int g = (isV ? (n0 - 256) : n0) >> 6;
        const int b = m0 >> 12, l0 = m0 & 4095;
        u16* sT = sAB;
        __syncthreads();
        if (isV) {
            float mfl[4];
#pragma unroll
            for (int r = 0; r < 4; ++r)
                mfl[r] = maskp[b * 4096 + l0 + 16 * w + quad * 4 + r] ? 1.f : 0.f;
#pragma unroll
            for (int nt = 0; nt < 4; ++nt)
#pragma unroll
                for (int r = 0; r < 4; ++r) {
                    const int ml = 16 * w + quad * 4 + r, cl = nt * 16 + r16;
                    union { _Float16 h; u16 u; } cv;
                    cv.h = (_Float16)(acc[nt][r] * mfl[r]);
                    sT[cl * 72 + ml] = cv.u;           // V^T tile: row=d, col=l
                }
        } else {
#pragma unroll
            for (int nt = 0; nt < 4; ++nt)
#pragma unroll
                for (int r = 0; r < 4; ++r) {
                    const int ml = 16 * w + quad * 4 + r, cl = nt * 16 + r16;
                    sT[ml * 72 + cl] = f2bf(acc[nt][r]);   // K tile: row=l, col=d
                }
        }
        __syncthreads();
#pragma unroll
        for (int p = 0; p < 2; ++p) {
            const int idx = t + 256 * p, rr = idx >> 3, ch = idx & 7;
            const int4 v = *(const int4*)(sT + rr * 72 + ch * 8);
            if (isV)
                *(int4*)(outV + ((size_t)(b * 4 + g) * 64 + rr) * 4096 + l0 + ch * 8) = v;
            else
                *(int4*)(outK + (((size_t)(b * 4 + g) * 4096 + l0 + rr) << 6) + ch * 8) = v;
        }
    } else {                                           // MODE 3: plain fp32
#pragma unroll
        for (int nt = 0; nt < 4; ++nt)
#pragma unroll
            for (int r = 0; r < 4; ++r) {
                const int m = m0 + 16 * w + quad * 4 + r;
                const int c = n0 + nt * 16 + r16;
                out_f[(size_t)m * 1024 + c] = acc[nt][r];
            }
    }
}

// n-inner swizzle: consecutive WGs share the same A-tile (L2 reuse)
__global__ __launch_bounds__(256) void gemm_qkv(const u16* __restrict__ poolb,
                                                const u16* __restrict__ encb,
                                                const u16* __restrict__ Wq_t,
                                                const u16* __restrict__ Wkv_t,
                                                const int* __restrict__ maskp,
                                                u16* __restrict__ Qa,
                                                u16* __restrict__ Ka,
                                                u16* __restrict__ Va) {
    const int bx = blockIdx.x;
    if (bx < 1024) {
        gemm_core<4>(encb, Wkv_t, maskp, Ka, Va, nullptr, (bx >> 3) * 64, (bx & 7) * 64, 0, 16);
    } else {
        const int b = bx - 1024;
        gemm_core<0>(poolb, Wq_t, nullptr, Qa, nullptr, nullptr, (b >> 4) * 64, (b & 15) * 64, 0, 16);
    }
}

// split-K-4: grid 1024, each WG does 4 K-iters, writes fp32 partial tile
__global__ __launch_bounds__(256) void gemm_o(const u16* __restrict__ attn,
                                              const u16* __restrict__ Wo_t,
                                              float* __restrict__ blkpart) {
    const int bx = blockIdx.x;
    const int s = bx >> 8, m0 = ((bx >> 4) & 15) * 64, n0 = (bx & 15) * 64;
    gemm_core<3>(attn, Wo_t, nullptr, nullptr, nullptr,
                 blkpart + ((size_t)s << 20), m0, n0, s * 4, 4);
}

// ---------------- flash attention: LDS-staged, in-register P ---------------
// grid 1024: bx = ((b*4+g)*4+split)*32 + s16. Waves = 4 qh sharing the staged
// K/V tile. S^T = K·Q^T; p = exp2 -> f16 A-frags; O += P·V; L += P·m.
__global__ __launch_bounds__(256, 4) void flash_attn(const u16* __restrict__ Qa,
                                                     const u16* __restrict__ Ka,
                                                     const u16* __restrict__ Vt,
                                                     const u16* __restrict__ mh,
                                                     float* __restrict__ Opart,
                                                     float* __restrict__ mlpart) {
    const int bx = blockIdx.x;
    const int s16 = bx & 31, rr = bx >> 5;
    const int split = rr & 3, gb = rr >> 2;
    const int g = gb & 3, b = gb >> 2;
    __shared__ __align__(16) u16 sK[64 * 72];        // [l][d] bf16
    __shared__ __align__(16) u16 sV[64 * 68];        // [d][l] f16 (V^T)
    const int t = threadIdx.x;
    const int qh = t >> 6, lane = t & 63, quad = lane >> 4, r16 = lane & 15;

    bf16x8 aq[2];
    {
        const size_t qbase = ((((size_t)(b * 4 + g) * 4 + qh) * 512) + s16 * 16 + r16) * 64;
#pragma unroll
        for (int kk = 0; kk < 2; ++kk)
            aq[kk] = *(const bf16x8*)(Qa + qbase + kk * 32 + quad * 8);
    }
    const u16* Kg = Ka + (size_t)(b * 4 + g) * 4096 * 64 + (size_t)split * 1024 * 64; // [l][d]
    const u16* Vg = Vt + (size_t)(b * 4 + g) * 64 * 4096 + split * 1024;              // [d][l]
    const u16* mb = mh + b * 4096 + split * 1024 + quad * 4;

    f32x4 o[4], lacc;
#pragma unroll
    for (int i = 0; i < 4; ++i) o[i] = (f32x4){0.f, 0.f, 0.f, 0.f};
    lacc = (f32x4){0.f, 0.f, 0.f, 0.f};

    for (int tile = 0; tile < 16; ++tile) {
        const int l0 = tile * 64;
        __syncthreads();
#pragma unroll
        for (int p = 0; p < 2; ++p) {
            const int idx = t + 256 * p, row = idx >> 3, seg = idx & 7;
            *(int4*)(sK + row * 72 + seg * 8) =
                *(const int4*)(Kg + (size_t)(l0 + row) * 64 + seg * 8);
            *(int4*)(sV + row * 68 + seg * 8) =
                *(const int4*)(Vg + (size_t)row * 4096 + l0 + seg * 8);
        }
        __syncthreads();

        // S^T[l][q]: K frags from LDS as A-operand, Q regs as B
        f32x4 st[4];
#pragma unroll
        for (int nt = 0; nt < 4; ++nt) st[nt] = (f32x4){0.f, 0.f, 0.f, 0.f};
#pragma unroll
        for (int kk = 0; kk < 2; ++kk)
#pragma unroll
            for (int nt = 0; nt < 4; ++nt) {
                const bf16x8 ka = *(const bf16x8*)(sK + (nt * 16 + r16) * 72 + kk * 32 + quad * 8);
                st[nt] = __builtin_amdgcn_mfma_f32_16x16x32_bf16(ka, aq[kk], st[nt], 0, 0, 0);
            }

        // p = exp2(s) -> f16 A-frags (P[q][l-chunk]); L and O via MFMA
#pragma unroll
        for (int nt = 0; nt < 4; ++nt) {
            f16x4 pa;
#pragma unroll
            for (int j = 0; j < 4; ++j)
                pa[j] = (_Float16)__builtin_amdgcn_exp2f(st[nt][j]);
            const f16x4 bvm = *(const f16x4*)(mb + l0 + nt * 16);
            lacc = __builtin_amdgcn_mfma_f32_16x16x16f16(pa, bvm, lacc, 0, 0, 0);
#pragma unroll
            for (int dt = 0; dt < 4; ++dt) {
                const f16x4 bv = *(const f16x4*)(sV + (dt * 16 + r16) * 68 + nt * 16 + quad * 4);
                o[dt] = __builtin_amdgcn_mfma_f32_16x16x16f16(pa, bv, o[dt], 0, 0, 0);
            }
        }
    }

    // D layout: row(quad*4+r) = query q, col(r16) = d (o) / replicated (lacc)
    const size_t pbase = ((size_t)bx * 4 + qh) * 1024;
#pragma unroll
    for (int dt = 0; dt < 4; ++dt)
#pragma unroll
        for (int r = 0; r < 4; ++r)
            Opart[pbase + (size_t)(quad * 4 + r) * 64 + dt * 16 + r16] = o[dt][r];
    if (r16 == 0) {
#pragma unroll
        for (int r = 0; r < 4; ++r)
            mlpart[((size_t)bx * 4 + qh) * 16 + quad * 4 + r] = lacc[r];
    }
}

// ---------------- combine 4 split partials -> normalized attn (bf16) -------
__global__ __launch_bounds__(256) void flash_combine(const float* __restrict__ Opart,
                                                     const float* __restrict__ mlpart,
                                                     u16* __restrict__ attnout) {
    const int bx = blockIdx.x;                  // tile (b,g,qh,s16)
    const int s16 = bx & 31, h = bx >> 5;
    const int qh = h & 3, g = (h >> 2) & 3, b = h >> 4;
    const int t = threadIdx.x;
    const int q = t >> 4, dg = t & 15;
    float4 a = make_float4(0.f, 0.f, 0.f, 0.f);
    float L = 0.f;
#pragma unroll
    for (int s = 0; s < 4; ++s) {
        const size_t part = (((size_t)((b * 4 + g) * 4 + s) * 32 + s16) * 4 + qh);
        const float4 v = *(const float4*)(Opart + part * 1024 + q * 64 + dg * 4);
        a.x += v.x; a.y += v.y; a.z += v.z; a.w += v.w;
        L += mlpart[part * 16 + q];
    }
    const float invL = 1.f / L;
    ushort4 ov;
    ov.x = f2bf(a.x * invL); ov.y = f2bf(a.y * invL);
    ov.z = f2bf(a.z * invL); ov.w = f2bf(a.w * invL);
    *(ushort4*)(attnout + ((size_t)b * 512 + s16 * 16 + q) * 1024 +
                (g * 4 + qh) * 64 + dg * 4) = ov;
}

// ---------------- sum split-K partials + broadcast x16 ---------------------
// one thread per block-row float4: 4 partial reads, 16 coalesced stores
__global__ __launch_bounds__(256) void bcast_out(const float* __restrict__ blkpart,
                                                 float* __restrict__ out) {
    const int tid = blockIdx.x * 256 + threadIdx.x;   // 262144
    const int c4 = tid & 255;
    const int row = tid >> 8;                          // b*512 + n
    float4 a = make_float4(0.f, 0.f, 0.f, 0.f);
#pragma unroll
    for (int s = 0; s < 4; ++s) {
        const float4 v = ((const float4*)blkpart)[(s << 18) + (row << 8) + c4];
        a.x += v.x; a.y += v.y; a.z += v.z; a.w += v.w;
    }
    const int b = row >> 9, n = row & 511;
    float4* dst = (float4*)out + (((size_t)b * 8192 + n * 16) << 8) + c4;
#pragma unroll
    for (int rep = 0; rep < 16; ++rep)
        dst[(size_t)rep << 8] = a;
}

// ---------------------------------------------------------------------------
extern "C" void kernel_launch(void* const* d_in, const int* in_sizes, int n_in,
                              void* d_out, int out_size, void* d_ws, size_t ws_size,
                              hipStream_t stream) {
    const float* hid  = (const float*)d_in[0];
    const float* enc  = (const float*)d_in[1];
    const int*   mask = (const int*)d_in[2];
    const float* Wq   = (const float*)d_in[3];
    const float* Wk   = (const float*)d_in[4];
    const float* Wv   = (const float*)d_in[5];
    const float* Wo   = (const float*)d_in[6];
    float* out = (float*)d_out;

    char* ws = (char*)d_ws;
    size_t off = 0;
    auto alloc = [&](size_t bytes) -> char* {
        char* p = ws + off;
        off += (bytes + 255) & ~(size_t)255;
        return p;
    };
    u16* Wq_t  = (u16*)alloc((size_t)1024 * 1024 * 2);
    u16* Wkv_t = (u16*)alloc((size_t)512 * 1024 * 2);
    u16* Wo_t  = (u16*)alloc((size_t)1024 * 1024 * 2);
    u16* encb  = (u16*)alloc((size_t)8192 * 1024 * 2);     // 16 MB
    u16* poolb = (u16*)alloc((size_t)1024 * 1024 * 2);     // 2 MB
    u16* Qa    = (u16*)alloc((size_t)1024 * 1024 * 2);
    u16* Ka    = (u16*)alloc((size_t)8 * 4096 * 64 * 2);   // bf16 [l][d]
    u16* Va    = (u16*)alloc((size_t)8 * 4096 * 64 * 2);   // f16  [d][l], masked
    u16* attn  = (u16*)alloc((size_t)1024 * 1024 * 2);
    u16* mh    = (u16*)alloc((size_t)8192 * 2);            // f16 0/1 mask
    // stream-ordered aliases of encb (16 MB):
    //   flash writes Opart -> combine reads Opart -> gemm_o writes blkpart
    //   -> bcast reads blkpart.  mlpart aliases poolb (dead after Q-GEMM).
    float* Opart   = (float*)encb;   // 4096 tiles x 16x64 fp32 = 16 MB
    float* blkpart = (float*)encb;   // 4 x 1024 x 1024 fp32 = 16 MB
    float* mlpart  = (float*)poolb;  // 4096 x 16 fp32 = 256 KB

    prep_all<<<5633, 256, 0, stream>>>(enc, hid, mask, Wq, Wk, Wv, Wo,
                                       encb, poolb, mh, Wq_t, Wkv_t, Wo_t);
    gemm_qkv<<<1280, 256, 0, stream>>>(poolb, encb, Wq_t, Wkv_t, mask, Qa, Ka, Va);
    flash_attn<<<1024, 256, 0, stream>>>(Qa, Ka, Va, mh, Opart, mlpart);
    flash_combine<<<1024, 256, 0, stream>>>(Opart, mlpart, attn);
    gemm_o<<<1024, 256, 0, stream>>>(attn, Wo_t, blkpart);
    bcast_out<<<1024, 256, 0, stream>>>(blkpart, out);
}

// Round 10
// 243.634 us; speedup vs baseline: 1.6369x; 1.0200x over previous
//
#include <hip/hip_runtime.h>

// ---------------------------------------------------------------------------
// BlockCrossAttention on MI355X (gfx950).  Round 10 (= r9 + two fixes):
//  - prep_all: heavy-first block order (pool -> enc -> transposes -> mask) so
//    the 64KB-read pool blocks overlap the light tail instead of running as a
//    starved final phase.
//  - KV projection: 128x64 tiles (MFMA/staging ratio 8 -> 10.7), grid 512;
//    Q stays 64x64 in the same launch. Epilogues adapted to 128-row tiles.
//  - flash / combine / gemm_o / bcast unchanged from r9.
// ---------------------------------------------------------------------------

typedef unsigned short u16;
typedef __attribute__((ext_vector_type(8))) __bf16 bf16x8;
typedef __attribute__((ext_vector_type(4))) float f32x4;
typedef __attribute__((ext_vector_type(4))) _Float16 f16x4;

static __device__ __forceinline__ u16 f2bf(float f) {        // RNE
    unsigned int u = __float_as_uint(f);
    u = (u + 0x7fffu + ((u >> 16) & 1u)) >> 16;
    return (u16)u;
}
static __device__ __forceinline__ void gload16(const u16* g, u16* l) {
    __builtin_amdgcn_global_load_lds(
        (const __attribute__((address_space(1))) void*)g,
        (__attribute__((address_space(3))) void*)l, 16, 0, 0);
}

// ---------------- all prep in one launch (heavy-first) ---------------------
// [0,1024) pool, [1024,3072) enc cast (x4 ILP), [3072,5632) transposes,
// 5632: mask -> f16 0/1.
__global__ __launch_bounds__(256) void prep_all(const float* __restrict__ enc,
                                                const float* __restrict__ hid,
                                                const int* __restrict__ mask,
                                                const float* __restrict__ Wq,
                                                const float* __restrict__ Wk,
                                                const float* __restrict__ Wv,
                                                const float* __restrict__ Wo,
                                                u16* __restrict__ encb,
                                                u16* __restrict__ poolb,
                                                u16* __restrict__ mh,
                                                u16* __restrict__ Wq_t,
                                                u16* __restrict__ Wkv_t,
                                                u16* __restrict__ Wo_t) {
    int bid = blockIdx.x;
    if (bid < 1024) {                                  // mean-pool 16 tokens
        const int tid = bid * 256 + threadIdx.x;
        const int c4 = tid & 255;
        const int row = tid >> 8;                      // b*512 + n
        const float4* src = (const float4*)(hid + (size_t)row * 16 * 1024) + c4;
        float4 a = src[0];
#pragma unroll
        for (int t = 1; t < 16; ++t) {
            float4 b = src[(size_t)t * 256];
            a.x += b.x; a.y += b.y; a.z += b.z; a.w += b.w;
        }
        ushort4 o;
        o.x = f2bf(a.x * 0.0625f); o.y = f2bf(a.y * 0.0625f);
        o.z = f2bf(a.z * 0.0625f); o.w = f2bf(a.w * 0.0625f);
        *(ushort4*)(poolb + (size_t)row * 1024 + c4 * 4) = o;
    } else if (bid < 3072) {                           // enc fp32->bf16, x4 ILP
        const int base = (bid - 1024) * 1024 + threadIdx.x;
        float4 v[4];
#pragma unroll
        for (int j = 0; j < 4; ++j) v[j] = ((const float4*)enc)[base + j * 256];
#pragma unroll
        for (int j = 0; j < 4; ++j) {
            ushort4 o;
            o.x = f2bf(v[j].x); o.y = f2bf(v[j].y);
            o.z = f2bf(v[j].z); o.w = f2bf(v[j].w);
            ((ushort4*)encb)[base + j * 256] = o;
        }
    } else if (bid < 5632) {                           // weight transpose+cast
        bid -= 3072;
        const float* in; u16* out; int N, nbx, rowoff;
        if (bid < 1024)      { in = Wq; out = Wq_t;  N = 1024; nbx = 32; rowoff = 0; }
        else if (bid < 2048) { in = Wo; out = Wo_t;  N = 1024; nbx = 32; rowoff = 0; bid -= 1024; }
        else if (bid < 2304) { in = Wk; out = Wkv_t; N = 256;  nbx = 8;  rowoff = 0; bid -= 2048; }
        else                 { in = Wv; out = Wkv_t; N = 256;  nbx = 8;  rowoff = 256; bid -= 2304; }
        const int n0 = (bid % nbx) * 32, k0 = (bid / nbx) * 32;
        __shared__ float t[32][33];
        const int tx = threadIdx.x & 31, ty = threadIdx.x >> 5;
#pragma unroll
        for (int i = 0; i < 4; ++i)
            t[ty + 8 * i][tx] = in[(size_t)(k0 + ty + 8 * i) * N + n0 + tx];
        __syncthreads();
#pragma unroll
        for (int i = 0; i < 4; ++i)
            out[(size_t)(rowoff + n0 + ty + 8 * i) * 1024 + k0 + tx] = f2bf(t[tx][ty + 8 * i]);
    } else {                                           // mask -> f16 0/1
#pragma unroll
        for (int k = 0; k < 32; ++k) {
            const int i = threadIdx.x + 256 * k;
            mh[i] = mask[i] ? (u16)0x3C00 : (u16)0;    // f16 1.0 / 0.0
        }
    }
}

// ---------------- 64x64 GEMM core (shared mem passed in) -------------------
// MODE 0: Q -> Qa scatter * 0.125*log2e.  MODE 3: fp32 out[m*1024+c].
template <int MODE>
static __device__ __forceinline__ void gemm_core(const u16* __restrict__ A,
                                                 const u16* __restrict__ Bt,
                                                 u16* __restrict__ outQ,
                                                 float* __restrict__ out_f,
                                                 int m0, int n0, int kt0, int nkt,
                                                 u16* sAB) {
    u16* sA = sAB;
    u16* sB = sAB + 64 * 64;
    const int t = threadIdx.x;
    const int w = t >> 6, lane = t & 63, quad = lane >> 4, r16 = lane & 15;
    const int row8 = lane >> 3, seg = lane & 7;

    f32x4 acc[4];
#pragma unroll
    for (int i = 0; i < 4; ++i) acc[i] = (f32x4){0.f, 0.f, 0.f, 0.f};

    for (int kt = kt0; kt < kt0 + nkt; ++kt) {
        const int k0 = kt * 64;
        __syncthreads();
#pragma unroll
        for (int j = 0; j < 2; ++j) {
            const int ra = w * 16 + j * 8;
            gload16(A + (size_t)(m0 + ra + row8) * 1024 + k0 + seg * 8, sA + ra * 64);
            gload16(Bt + (size_t)(n0 + ra + row8) * 1024 + k0 + seg * 8, sB + ra * 64);
        }
        __syncthreads();
#pragma unroll
        for (int kk = 0; kk < 2; ++kk) {
            const bf16x8 af = *(const bf16x8*)(sA + (16 * w + r16) * 64 + kk * 32 + quad * 8);
#pragma unroll
            for (int nt = 0; nt < 4; ++nt) {
                const bf16x8 bfv = *(const bf16x8*)(sB + (nt * 16 + r16) * 64 + kk * 32 + quad * 8);
                acc[nt] = __builtin_amdgcn_mfma_f32_16x16x32_bf16(af, bfv, acc[nt], 0, 0, 0);
            }
        }
    }

    if (MODE == 0) {
#pragma unroll
        for (int nt = 0; nt < 4; ++nt)
#pragma unroll
            for (int r = 0; r < 4; ++r) {
                const int m = m0 + 16 * w + quad * 4 + r;
                const int c = n0 + nt * 16 + r16;
                const int b = m >> 9, nq = m & 511, g = c >> 8, qh = (c >> 6) & 3, d = c & 63;
                outQ[((((size_t)(b * 4 + g) * 4 + qh) * 512 + nq) << 6) + d] =
                    f2bf(acc[nt][r] * 0.180336880f);   // 0.125*log2(e), exp2 domain
            }
    } else {                                           // MODE 3: plain fp32
#pragma unroll
        for (int nt = 0; nt < 4; ++nt)
#pragma unroll
            for (int r = 0; r < 4; ++r) {
                const int m = m0 + 16 * w + quad * 4 + r;
                const int c = n0 + nt * 16 + r16;
                out_f[(size_t)m * 1024 + c] = acc[nt][r];
            }
    }
}

// ---------------- Q + KV projection in one launch --------------------------
// bx < 512: KV GEMM, 128x64 tile (m0 = (bx>>3)*128, n-inner swizzle).
// bx >= 512: Q GEMM, 64x64 tile.
__global__ __launch_bounds__(256) void gemm_qkv(const u16* __restrict__ poolb,
                                                const u16* __restrict__ encb,
                                                const u16* __restrict__ Wq_t,
                                                const u16* __restrict__ Wkv_t,
                                                const int* __restrict__ maskp,
                                                u16* __restrict__ Qa,
                                                u16* __restrict__ Ka,
                                                u16* __restrict__ Va) {
    __shared__ __align__(16) u16 smem[12288];          // 24 KB
    const int bx = blockIdx.x;
    if (bx >= 512) {
        const int b = bx - 512;
        gemm_core<0>(poolb, Wq_t, Qa, nullptr, (b >> 4) * 64, (b & 15) * 64, 0, 16, smem);
        return;
    }
    const int m0 = (bx >> 3) * 128, n0 = (bx & 7) * 64;
    u16* sA = smem;                                    // 128 x 64
    u16* sB = smem + 128 * 64;                         // 64 x 64
    const int t = threadIdx.x;
    const int w = t >> 6, lane = t & 63, quad = lane >> 4, r16 = lane & 15;
    const int row8 = lane >> 3, seg = lane & 7;

    f32x4 acc[2][4];
#pragma unroll
    for (int i = 0; i < 2; ++i)
#pragma unroll
        for (int nt = 0; nt < 4; ++nt) acc[i][nt] = (f32x4){0.f, 0.f, 0.f, 0.f};

    for (int kt = 0; kt < 16; ++kt) {
        const int k0 = kt * 64;
        __syncthreads();
#pragma unroll
        for (int p = 0; p < 4; ++p) {
            const int ra = p * 32 + w * 8;
            gload16(encb + (size_t)(m0 + ra + row8) * 1024 + k0 + seg * 8, sA + ra * 64);
        }
#pragma unroll
        for (int p = 0; p < 2; ++p) {
            const int ra = p * 32 + w * 8;
            gload16(Wkv_t + (size_t)(n0 + ra + row8) * 1024 + k0 + seg * 8, sB + ra * 64);
        }
        __syncthreads();
#pragma unroll
        for (int kk = 0; kk < 2; ++kk)
#pragma unroll
            for (int i = 0; i < 2; ++i) {
                const bf16x8 af = *(const bf16x8*)(sA + (w * 32 + i * 16 + r16) * 64 + kk * 32 + quad * 8);
#pragma unroll
                for (int nt = 0; nt < 4; ++nt) {
                    const bf16x8 bfv = *(const bf16x8*)(sB + (nt * 16 + r16) * 64 + kk * 32 + quad * 8);
                    acc[i][nt] = __builtin_amdgcn_mfma_f32_16x16x32_bf16(af, bfv, acc[i][nt], 0, 0, 0);
                }
            }
    }

    const bool isV = (n0 >= 256);
    const int g = (isV ? (n0 - 256) : n0) >> 6;
    const int b = m0 >> 12, l0 = m0 & 4095;
    __syncthreads();
    if (isV) {
        u16* sT = smem;                                // 64 d x stride 136 (l)
#pragma unroll
        for (int i = 0; i < 2; ++i) {
            float mfl[4];
#pragma unroll
            for (int r = 0; r < 4; ++r)
                mfl[r] = maskp[b * 4096 + l0 + w * 32 + i * 16 + quad * 4 + r] ? 1.f : 0.f;
#pragma unroll
            for (int nt = 0; nt < 4; ++nt)
#pragma unroll
                for (int r = 0; r < 4; ++r) {
                    const int ml = w * 32 + i * 16 + quad * 4 + r, cl = nt * 16 + r16;
                    union { _Float16 h; u16 u; } cv;
                    cv.h = (_Float16)(acc[i][nt][r] * mfl[r]);
                    sT[cl * 136 + ml] = cv.u;
                }
        }
        __syncthreads();
#pragma unroll
        for (int p = 0; p < 4; ++p) {
            const int idx = t + 256 * p, rr = idx >> 4, ch = idx & 15;
            *(int4*)(Va + ((size_t)(b * 4 + g) * 64 + rr) * 4096 + l0 + ch * 8) =
                *(const int4*)(sT + rr * 136 + ch * 8);
        }
    } else {
        u16* sT = smem;                                // 128 l x stride 72 (d)
#pragma unroll
        for (int i = 0; i < 2; ++i)
#pragma unroll
            for (int nt = 0; nt < 4; ++nt)
#pragma unroll
                for (int r = 0; r < 4; ++r) {
                    const int ml = w * 32 + i * 16 + quad * 4 + r, cl = nt * 16 + r16;
                    sT[ml * 72 + cl] = f2bf(acc[i][nt][r]);
                }
        __syncthreads();
#pragma unroll
        for (int p = 0; p < 4; ++p) {
            const int idx = t + 256 * p, rr = idx >> 3, ch = idx & 7;
            *(int4*)(Ka + (((size_t)(b * 4 + g) * 4096 + l0 + rr) << 6) + ch * 8) =
                *(const int4*)(sT + rr * 72 + ch * 8);
        }
    }
}

// split-K-4: grid 1024, each WG does 4 K-iters, writes fp32 partial tile
__global__ __launch_bounds__(256) void gemm_o(const u16* __restrict__ attn,
                                              const u16* __restrict__ Wo_t,
                                              float* __restrict__ blkpart) {
    __shared__ __align__(16) u16 smem[8192];           // 16 KB
    const int bx = blockIdx.x;
    const int s = bx >> 8, m0 = ((bx >> 4) & 15) * 64, n0 = (bx & 15) * 64;
    gemm_core<3>(attn, Wo_t, nullptr, blkpart + ((size_t)s << 20), m0, n0, s * 4, 4, smem);
}

// ---------------- flash attention: LDS-staged, in-register P ---------------
// grid 1024: bx = ((b*4+g)*4+split)*32 + s16. Waves = 4 qh sharing the staged
// K/V tile. S^T = K·Q^T; p = exp2 -> f16 A-frags; O += P·V; L += P·m.
__global__ __launch_bounds__(256, 4) void flash_attn(const u16* __restrict__ Qa,
                                                     const u16* __restrict__ Ka,
                                                     const u16* __restrict__ Vt,
                                                     const u16* __restrict__ mh,
                                                     float* __restrict__ Opart,
                                                     float* __restrict__ mlpart) {
    const int bx = blockIdx.x;
    const int s16 = bx & 31, rr = bx >> 5;
    const int split = rr & 3, gb = rr >> 2;
    const int g = gb & 3, b = gb >> 2;
    __shared__ __align__(16) u16 sK[64 * 72];        // [l][d] bf16
    __shared__ __align__(16) u16 sV[64 * 68];        // [d][l] f16 (V^T)
    const int t = threadIdx.x;
    const int qh = t >> 6, lane = t & 63, quad = lane >> 4, r16 = lane & 15;

    bf16x8 aq[2];
    {
        const size_t qbase = ((((size_t)(b * 4 + g) * 4 + qh) * 512) + s16 * 16 + r16) * 64;
#pragma unroll
        for (int kk = 0; kk < 2; ++kk)
            aq[kk] = *(const bf16x8*)(Qa + qbase + kk * 32 + quad * 8);
    }
    const u16* Kg = Ka + (size_t)(b * 4 + g) * 4096 * 64 + (size_t)split * 1024 * 64; // [l][d]
    const u16* Vg = Vt + (size_t)(b * 4 + g) * 64 * 4096 + split * 1024;              // [d][l]
    const u16* mb = mh + b * 4096 + split * 1024 + quad * 4;

    f32x4 o[4], lacc;
#pragma unroll
    for (int i = 0; i < 4; ++i) o[i] = (f32x4){0.f, 0.f, 0.f, 0.f};
    lacc = (f32x4){0.f, 0.f, 0.f, 0.f};

    for (int tile = 0; tile < 16; ++tile) {
        const int l0 = tile * 64;
        __syncthreads();
#pragma unroll
        for (int p = 0; p < 2; ++p) {
            const int idx = t + 256 * p, row = idx >> 3, seg = idx & 7;
            *(int4*)(sK + row * 72 + seg * 8) =
                *(const int4*)(Kg + (size_t)(l0 + row) * 64 + seg * 8);
            *(int4*)(sV + row * 68 + seg * 8) =
                *(const int4*)(Vg + (size_t)row * 4096 + l0 + seg * 8);
        }
        __syncthreads();

        // S^T[l][q]: K frags from LDS as A-operand, Q regs as B
        f32x4 st[4];
#pragma unroll
        for (int nt = 0; nt < 4; ++nt) st[nt] = (f32x4){0.f, 0.f, 0.f, 0.f};
#pragma unroll
        for (int kk = 0; kk < 2; ++kk)
#pragma unroll
            for (int nt = 0; nt < 4; ++nt) {
                const bf16x8 ka = *(const bf16x8*)(sK + (nt * 16 + r16) * 72 + kk * 32 + quad * 8);
                st[nt] = __builtin_amdgcn_mfma_f32_16x16x32_bf16(ka, aq[kk], st[nt], 0, 0, 0);
            }

        // p = exp2(s) -> f16 A-frags (P[q][l-chunk]); L and O via MFMA
#pragma unroll
        for (int nt = 0; nt < 4; ++nt) {
            f16x4 pa;
#pragma unroll
            for (int j = 0; j < 4; ++j)
                pa[j] = (_Float16)__builtin_amdgcn_exp2f(st[nt][j]);
            const f16x4 bvm = *(const f16x4*)(mb + l0 + nt * 16);
            lacc = __builtin_amdgcn_mfma_f32_16x16x16f16(pa, bvm, lacc, 0, 0, 0);
#pragma unroll
            for (int dt = 0; dt < 4; ++dt) {
                const f16x4 bv = *(const f16x4*)(sV + (dt * 16 + r16) * 68 + nt * 16 + quad * 4);
                o[dt] = __builtin_amdgcn_mfma_f32_16x16x16f16(pa, bv, o[dt], 0, 0, 0);
            }
        }
    }

    // D layout: row(quad*4+r) = query q, col(r16) = d (o) / replicated (lacc)
    const size_t pbase = ((size_t)bx * 4 + qh) * 1024;
#pragma unroll
    for (int dt = 0; dt < 4; ++dt)
#pragma unroll
        for (int r = 0; r < 4; ++r)
            Opart[pbase + (size_t)(quad * 4 + r) * 64 + dt * 16 + r16] = o[dt][r];
    if (r16 == 0) {
#pragma unroll
        for (int r = 0; r < 4; ++r)
            mlpart[((size_t)bx * 4 + qh) * 16 + quad * 4 + r] = lacc[r];
    }
}

// ---------------- combine 4 split partials -> normalized attn (bf16) -------
__global__ __launch_bounds__(256) void flash_combine(const float* __restrict__ Opart,
                                                     const float* __restrict__ mlpart,
                                                     u16* __restrict__ attnout) {
    const int bx = blockIdx.x;                  // tile (b,g,qh,s16)
    const int s16 = bx & 31, h = bx >> 5;
    const int qh = h & 3, g = (h >> 2) & 3, b = h >> 4;
    const int t = threadIdx.x;
    const int q = t >> 4, dg = t & 15;
    float4 a = make_float4(0.f, 0.f, 0.f, 0.f);
    float L = 0.f;
#pragma unroll
    for (int s = 0; s < 4; ++s) {
        const size_t part = (((size_t)((b * 4 + g) * 4 + s) * 32 + s16) * 4 + qh);
        const float4 v = *(const float4*)(Opart + part * 1024 + q * 64 + dg * 4);
        a.x += v.x; a.y += v.y; a.z += v.z; a.w += v.w;
        L += mlpart[part * 16 + q];
    }
    const float invL = 1.f / L;
    ushort4 ov;
    ov.x = f2bf(a.x * invL); ov.y = f2bf(a.y * invL);
    ov.z = f2bf(a.z * invL); ov.w = f2bf(a.w * invL);
    *(ushort4*)(attnout + ((size_t)b * 512 + s16 * 16 + q) * 1024 +
                (g * 4 + qh) * 64 + dg * 4) = ov;
}

// ---------------- sum split-K partials + broadcast x16 ---------------------
__global__ __launch_bounds__(256) void bcast_out(const float* __restrict__ blkpart,
                                                 float* __restrict__ out) {
    const int tid = blockIdx.x * 256 + threadIdx.x;   // 262144
    const int c4 = tid & 255;
    const int row = tid >> 8;                          // b*512 + n
    float4 a = make_float4(0.f, 0.f, 0.f, 0.f);
#pragma unroll
    for (int s = 0; s < 4; ++s) {
        const float4 v = ((const float4*)blkpart)[(s << 18) + (row << 8) + c4];
        a.x += v.x; a.y += v.y; a.z += v.z; a.w += v.w;
    }
    const int b = row >> 9, n = row & 511;
    float4* dst = (float4*)out + (((size_t)b * 8192 + n * 16) << 8) + c4;
#pragma unroll
    for (int rep = 0; rep < 16; ++rep)
        dst[(size_t)rep << 8] = a;
}

// ---------------------------------------------------------------------------
extern "C" void kernel_launch(void* const* d_in, const int* in_sizes, int n_in,
                              void* d_out, int out_size, void* d_ws, size_t ws_size,
                              hipStream_t stream) {
    const float* hid  = (const float*)d_in[0];
    const float* enc  = (const float*)d_in[1];
    const int*   mask = (const int*)d_in[2];
    const float* Wq   = (const float*)d_in[3];
    const float* Wk   = (const float*)d_in[4];
    const float* Wv   = (const float*)d_in[5];
    const float* Wo   = (const float*)d_in[6];
    float* out = (float*)d_out;

    char* ws = (char*)d_ws;
    size_t off = 0;
    auto alloc = [&](size_t bytes) -> char* {
        char* p = ws + off;
        off += (bytes + 255) & ~(size_t)255;
        return p;
    };
    u16* Wq_t  = (u16*)alloc((size_t)1024 * 1024 * 2);
    u16* Wkv_t = (u16*)alloc((size_t)512 * 1024 * 2);
    u16* Wo_t  = (u16*)alloc((size_t)1024 * 1024 * 2);
    u16* encb  = (u16*)alloc((size_t)8192 * 1024 * 2);     // 16 MB
    u16* poolb = (u16*)alloc((size_t)1024 * 1024 * 2);     // 2 MB
    u16* Qa    = (u16*)alloc((size_t)1024 * 1024 * 2);
    u16* Ka    = (u16*)alloc((size_t)8 * 4096 * 64 * 2);   // bf16 [l][d]
    u16* Va    = (u16*)alloc((size_t)8 * 4096 * 64 * 2);   // f16  [d][l], masked
    u16* attn  = (u16*)alloc((size_t)1024 * 1024 * 2);
    u16* mh    = (u16*)alloc((size_t)8192 * 2);            // f16 0/1 mask
    // stream-ordered aliases of encb (16 MB):
    //   flash writes Opart -> combine reads Opart -> gemm_o writes blkpart
    //   -> bcast reads blkpart.  mlpart aliases poolb (dead after Q-GEMM).
    float* Opart   = (float*)encb;   // 4096 tiles x 16x64 fp32 = 16 MB
    float* blkpart = (float*)encb;   // 4 x 1024 x 1024 fp32 = 16 MB
    float* mlpart  = (float*)poolb;  // 4096 x 16 fp32 = 256 KB

    prep_all<<<5633, 256, 0, stream>>>(enc, hid, mask, Wq, Wk, Wv, Wo,
                                       encb, poolb, mh, Wq_t, Wkv_t, Wo_t);
    gemm_qkv<<<768, 256, 0, stream>>>(poolb, encb, Wq_t, Wkv_t, mask, Qa, Ka, Va);
    flash_attn<<<1024, 256, 0, stream>>>(Qa, Ka, Va, mh, Opart, mlpart);
    flash_combine<<<1024, 256, 0, stream>>>(Opart, mlpart, attn);
    gemm_o<<<1024, 256, 0, stream>>>(attn, Wo_t, blkpart);
    bcast_out<<<1024, 256, 0, stream>>>(blkpart, out);
}